// Round 7
// baseline (657.599 us; speedup 1.0000x reference)
//
#include <hip/hip_runtime.h>
#include <hip/hip_fp16.h>
#include <float.h>

#define DECAY 0.99f
#define OMD   0.01f
#define EPSF  1e-6f

constexpr int Bb = 8, Ss = 8192, Dd = 256, Kk = 2048;
constexpr int Nn = Bb * Ss;                 // 65536 rows

// ---- output layout (floats) ----
constexpr long OUT_QUANT = 0;                         // 16777216 floats
constexpr long OUT_IND   = (long)Nn * Dd;             // 16777216
constexpr long OUT_NCS   = OUT_IND + Nn;              // 16842752
constexpr long OUT_NEA   = OUT_NCS + Kk;              // 16844800
constexpr long OUT_NE    = OUT_NEA + (long)Kk * Dd;   // 17369088

// ---- workspace layout (floats) ----
constexpr long WS_COUNTS = 0;                         // K
constexpr long WS_TOTAL  = 2048;                      // 1
constexpr long WS_EE     = 2112;                      // K
constexpr long WS_BIG    = 4160;                      // embed_sum (atomic path)
                                                      // or 8 partials (ws path)
constexpr int  PARTS     = 8;                         // strip split for segsum
constexpr int  CODES     = 8;                         // codes per segsum block

typedef __attribute__((ext_vector_type(8))) short short8;
typedef __attribute__((ext_vector_type(8))) _Float16 half8;
typedef __attribute__((ext_vector_type(4))) float floatx4;

// fp16 single-pass certainty window: per-dist error std ~0.018, realistic max
// over all rows ~0.13; rows whose approx top-2 gap <= WINDOW get an exact
// fp32 rescan in pass 2. 0.5 = ~20 sigma margin. Also makes the cross-wave
// merge order tie-safe: any near-tie (<=WINDOW) is rescanned exactly.
#define WINDOW 0.5f

__device__ __forceinline__ ushort f2h(float v)
{
    __half h = __float2half(v);
    return *(ushort*)&h;
}

// ============================================================
// Kernel B: embed -> e_h (fp16), ee[k] = sum_d embed[k][d]^2, and
// (block 0) reset the pass-2 ambiguity queue counter.
// ============================================================
__global__ __launch_bounds__(256) void convert_e_kernel(
    const float* __restrict__ embed, ushort* __restrict__ e_h,
    float* __restrict__ ee, int* __restrict__ qbase)
{
    if (blockIdx.x == 0 && threadIdx.x == 0) qbase[0] = 0;
    int row  = blockIdx.x * 4 + (threadIdx.x >> 6);
    int lane = threadIdx.x & 63;
    long base = (long)row * Dd + lane * 4;
    float4 v = *(const float4*)&embed[base];
    float s = v.x * v.x + v.y * v.y + v.z * v.z + v.w * v.w;
    ushort4 h;
    h.x = f2h(v.x); h.y = f2h(v.y); h.z = f2h(v.z); h.w = f2h(v.w);
    *(ushort4*)&e_h[base] = h;
    #pragma unroll
    for (int off = 32; off >= 1; off >>= 1)
        s += __shfl_xor(s, off, 64);
    if (lane == 0) ee[row] = s;
}

// ============================================================
// Kernel C (pass 1): fp16 MFMA distance + top-2 argmin + fused quant gather.
//
// v9 (round 7): A-in-registers, zero main-loop LDS, code-split waves.
//  * Round-6 diagnosis: af re-read from LDS every ct (512 b128/wave) +
//    B L2 latency exposed with only 2 waves/EU -> MfmaUtil 15%.
//  * Now: wave owns 32 rows; A fragments live in 64 VGPRs, loaded ONCE
//    from x (fp32, fused fp16 convert; full-line-efficient). Waves split
//    the code axis: wave (rg,part) covers rows rg*32..+32, codes
//    part*1024..+1024 -> 4096 waves = 16/CU available; waves_per_eu(3,3)
//    with ~150 VGPR -> 3 waves/EU resident.
//  * Main loop per 16-code tile: 8 half8 B loads (L2-resident e_h,
//    perfectly coalesced) -> 16 MFMA -> 8 top-2 updates. No LDS, no
//    barriers -> compiler pipelines loads across tiles.
//  * Epilogue: 16-lane top-2 shfl reduce, 2-partition LDS merge,
//    fused quant gather (pass2 rewrites queued rows).
// ============================================================
__global__ __attribute__((amdgpu_waves_per_eu(3, 3))) __launch_bounds__(256)
void pass1_kernel(
    const float* __restrict__ x, const ushort* __restrict__ e_h,
    const float* __restrict__ embed, const float* __restrict__ ee,
    float* __restrict__ ind_out, float* __restrict__ quant,
    int* __restrict__ qbase)
{
    __shared__ float redv[2][64];
    __shared__ float red2[2][64];
    __shared__ int   redi[2][64];
    __shared__ int   idxs[64];

    const int tid  = threadIdx.x;
    const int lane = tid & 63;
    const int quad = lane >> 4;
    const int l15  = lane & 15;
    const int w    = tid >> 6;
    const int part = w & 1;          // code partition (0: 0..1023, 1: 1024..2047)
    const int rg   = w >> 1;         // row group (32 rows each)
    const long row0  = (long)blockIdx.x * 64;
    const long row0w = row0 + rg * 32;

    // ---- A fragments in registers (loaded once) ----
    // af{0,1}[ks]: row = row0w + rt*16 + l15, k = ks*32 + quad*8 .. +8
    half8 af0[8], af1[8];
    {
        const long ra0 = (row0w + l15) << 8;
        const long ra1 = (row0w + 16 + l15) << 8;
        #pragma unroll
        for (int ks = 0; ks < 8; ++ks) {
            const int off = ks * 32 + quad * 8;
            float4 a = *(const float4*)&x[ra0 + off];
            float4 b = *(const float4*)&x[ra0 + off + 4];
            half8 h;
            h[0] = (_Float16)a.x; h[1] = (_Float16)a.y;
            h[2] = (_Float16)a.z; h[3] = (_Float16)a.w;
            h[4] = (_Float16)b.x; h[5] = (_Float16)b.y;
            h[6] = (_Float16)b.z; h[7] = (_Float16)b.w;
            af0[ks] = h;
            float4 c = *(const float4*)&x[ra1 + off];
            float4 d = *(const float4*)&x[ra1 + off + 4];
            half8 g;
            g[0] = (_Float16)c.x; g[1] = (_Float16)c.y;
            g[2] = (_Float16)c.z; g[3] = (_Float16)c.w;
            g[4] = (_Float16)d.x; g[5] = (_Float16)d.y;
            g[6] = (_Float16)d.z; g[7] = (_Float16)d.w;
            af1[ks] = g;
        }
    }

    float bestv[8], best2v[8];
    int   besti[8];
    #pragma unroll
    for (int i = 0; i < 8; ++i) { bestv[i] = FLT_MAX; best2v[i] = FLT_MAX; besti[i] = 0; }

    // B stream base: code = part*1024 + ct*16 + l15, k-chunk = quad
    const ushort* bbase = e_h + (((long)part * 1024 + l15) << 8) + quad * 8;
    const float*  eeb   = ee + part * 1024 + l15;

    for (int ct = 0; ct < 64; ++ct) {
        half8 bf[8];
        #pragma unroll
        for (int ks = 0; ks < 8; ++ks)
            bf[ks] = *(const half8*)&bbase[ct * 4096 + ks * 32];
        float eec = eeb[ct * 16];

        floatx4 acc0 = (floatx4){0.f, 0.f, 0.f, 0.f};
        floatx4 acc1 = (floatx4){0.f, 0.f, 0.f, 0.f};
        #pragma unroll
        for (int ks = 0; ks < 8; ++ks) {
            acc0 = __builtin_amdgcn_mfma_f32_16x16x32_f16(af0[ks], bf[ks], acc0, 0, 0, 0);
            acc1 = __builtin_amdgcn_mfma_f32_16x16x32_f16(af1[ks], bf[ks], acc1, 0, 0, 0);
        }

        const int cc = part * 1024 + ct * 16 + l15;
        #pragma unroll
        for (int reg = 0; reg < 4; ++reg) {
            float s = fmaf(-2.0f, acc0[reg], eec);
            if (s < bestv[reg]) {
                best2v[reg] = bestv[reg]; bestv[reg] = s; besti[reg] = cc;
            } else {
                best2v[reg] = fminf(best2v[reg], s);
            }
            float t = fmaf(-2.0f, acc1[reg], eec);
            const int sl = 4 + reg;
            if (t < bestv[sl]) {
                best2v[sl] = bestv[sl]; bestv[sl] = t; besti[sl] = cc;
            } else {
                best2v[sl] = fminf(best2v[sl], t);
            }
        }
    }

    // 16-lane top-2 reduce (codes within this wave's partition)
    #pragma unroll
    for (int slot = 0; slot < 8; ++slot) {
        float bv = bestv[slot]; int bi = besti[slot]; float b2 = best2v[slot];
        #pragma unroll
        for (int off = 8; off >= 1; off >>= 1) {
            float ov  = __shfl_xor(bv, off, 16);
            int   oi  = __shfl_xor(bi, off, 16);
            float ov2 = __shfl_xor(b2, off, 16);
            float nm2 = fminf(fminf(b2, ov2), fmaxf(bv, ov));
            if (ov < bv) { bv = ov; bi = oi; }
            b2 = nm2;
        }
        bestv[slot] = bv; besti[slot] = bi; best2v[slot] = b2;
    }

    if (l15 == 0) {
        #pragma unroll
        for (int rt = 0; rt < 2; ++rt)
            #pragma unroll
            for (int reg = 0; reg < 4; ++reg) {
                int r = rg * 32 + rt * 16 + quad * 4 + reg;   // 0..63 in block
                int slot = rt * 4 + reg;
                redv[part][r] = bestv[slot];
                red2[part][r] = best2v[slot];
                redi[part][r] = besti[slot];
            }
    }
    __syncthreads();

    // merge the 2 code partitions per row; near-ties (<=WINDOW) are queued
    // for pass2's exact lowest-index rescan -> merge order tie-safe.
    if (tid < 64) {
        float v0 = redv[0][tid], v1 = redv[1][tid];
        float s0 = red2[0][tid], s1 = red2[1][tid];
        float m1, m2; int mi;
        if (v0 <= v1) { m1 = v0; mi = redi[0][tid]; m2 = fminf(fminf(s0, s1), v1); }
        else          { m1 = v1; mi = redi[1][tid]; m2 = fminf(fminf(s0, s1), v0); }
        long rowAbs = row0 + tid;
        ind_out[rowAbs] = (float)mi;
        idxs[tid] = mi;
        if (m2 - m1 <= WINDOW) {
            int q = atomicAdd(qbase, 1);
            qbase[1 + q] = (int)rowAbs;
        }
    }
    __syncthreads();

    // ---- fused quant gather: quant[row] = embed[ind[row]] ----
    #pragma unroll
    for (int rr = 0; rr < 16; ++rr) {
        int r = w * 16 + rr;
        int idx = idxs[r];
        float4 ev = *(const float4*)&embed[(long)idx * Dd + lane * 4];
        *(float4*)&quant[(row0 + r) * Dd + lane * 4] = ev;
    }
}

// ============================================================
// Kernel D (pass 2): exact fp32 rescan of ambiguous rows (8-row batches),
// also rewriting quant for every queued row.
// v3 (round 7): LDS->VALU rebalance. Each thread handles 4 codes per
// d-iteration: 8 LDS broadcasts feed 128 FMAs (was 32) -> VALU-bound
// instead of LDS-throughput-bound (the hidden ~150-200us of round 6).
// Per-thread code order ascending -> lowest-index tie-break preserved.
// ============================================================
constexpr int RB = 8;
__global__ __launch_bounds__(256) void pass2_kernel(
    const float* __restrict__ x, const float* __restrict__ embed,
    const float* __restrict__ ee, const int* __restrict__ qbase,
    float* __restrict__ ind_out, float* __restrict__ quant)
{
    __shared__ float xs[RB][256];
    __shared__ float sv[RB][256];
    __shared__ int   si[RB][256];
    const int tid = threadIdx.x;
    const int count = qbase[0];

    for (int q0 = blockIdx.x * RB; q0 < count; q0 += gridDim.x * RB) {
        const int nr = (count - q0 < RB) ? (count - q0) : RB;
        __syncthreads();
        for (int r = 0; r < nr; ++r)
            xs[r][tid] = x[(long)qbase[1 + q0 + r] * Dd + tid];
        __syncthreads();

        float bv[RB]; int bi[RB];
        #pragma unroll
        for (int r = 0; r < RB; ++r) { bv[r] = FLT_MAX; bi[r] = 0; }

        #pragma unroll
        for (int g = 0; g < 2; ++g) {
            float dot[RB][4];
            #pragma unroll
            for (int r = 0; r < RB; ++r)
                #pragma unroll
                for (int j = 0; j < 4; ++j) dot[r][j] = 0.0f;

            for (int d = 0; d < Dd / 4; ++d) {
                float4 xv[RB];
                #pragma unroll
                for (int r = 0; r < RB; ++r)
                    xv[r] = *(const float4*)&xs[r][d * 4];
                #pragma unroll
                for (int j = 0; j < 4; ++j) {
                    const int c = g * 1024 + j * 256 + tid;
                    float4 e4 = *(const float4*)&embed[(long)c * Dd + d * 4];
                    #pragma unroll
                    for (int r = 0; r < RB; ++r)
                        dot[r][j] += e4.x * xv[r].x + e4.y * xv[r].y +
                                     e4.z * xv[r].z + e4.w * xv[r].w;
                }
            }
            #pragma unroll
            for (int j = 0; j < 4; ++j) {
                const int c = g * 1024 + j * 256 + tid;
                float eec = ee[c];
                #pragma unroll
                for (int r = 0; r < RB; ++r) {
                    float s = eec - 2.0f * dot[r][j];
                    if (s < bv[r]) { bv[r] = s; bi[r] = c; }
                }
            }
        }

        #pragma unroll
        for (int r = 0; r < RB; ++r) { sv[r][tid] = bv[r]; si[r][tid] = bi[r]; }
        __syncthreads();
        for (int off = 128; off >= 1; off >>= 1) {
            if (tid < off) {
                #pragma unroll
                for (int r = 0; r < RB; ++r) {
                    float v2 = sv[r][tid + off]; int i2 = si[r][tid + off];
                    if (v2 < sv[r][tid] || (v2 == sv[r][tid] && i2 < si[r][tid])) {
                        sv[r][tid] = v2; si[r][tid] = i2;
                    }
                }
            }
            __syncthreads();
        }
        if (tid < nr)
            ind_out[qbase[1 + q0 + tid]] = (float)si[tid][0];
        // rewrite quant for queued rows (exact final index)
        for (int r = 0; r < nr; ++r) {
            int code = si[r][0];
            long row = qbase[1 + q0 + r];
            quant[row * Dd + tid] = embed[(long)code * Dd + tid];
        }
        __syncthreads();
    }
}

// ============================================================
// Kernel F: pull-based segmented sum, CODES=8 codes per block.
// ============================================================
template <int USE_ATOMIC>
__global__ __launch_bounds__(256) void segsum_kernel(
    const float* __restrict__ x, const float* __restrict__ ind_f,
    float* __restrict__ dst, float* __restrict__ counts)
{
    __shared__ float part[CODES][4][256];   // 32KB
    __shared__ float cnt_l[CODES][4];
    const int tid  = threadIdx.x;
    const int w    = tid >> 6;
    const int lane = tid & 63;
    const int k0   = (blockIdx.x >> 3) * CODES;
    const int s    = blockIdx.x & 7;

    constexpr int STRIP = Nn / PARTS;          // 8192 rows
    constexpr int WAVE_ROWS = STRIP / 4;       // 2048 rows per wave
    const int base0 = s * STRIP + w * WAVE_ROWS;

    float4 acc[CODES];
    int    cnt[CODES];
    #pragma unroll
    for (int c = 0; c < CODES; ++c) { acc[c] = (float4){0.f,0.f,0.f,0.f}; cnt[c] = 0; }

    for (int win = 0; win < WAVE_ROWS; win += 64) {
        int idx = (int)ind_f[base0 + win + lane];
        unsigned rel = (unsigned)(idx - k0);
        unsigned long long m = __ballot(rel < (unsigned)CODES);
        while (m) {
            int l = __ffsll((unsigned long long)m) - 1;
            m &= m - 1;
            int code = __shfl((int)rel, l, 64);   // wave-uniform
            long row = base0 + win + l;
            float4 v = *(const float4*)&x[row * Dd + lane * 4];
            switch (code) {
                case 0: acc[0].x+=v.x; acc[0].y+=v.y; acc[0].z+=v.z; acc[0].w+=v.w; cnt[0]++; break;
                case 1: acc[1].x+=v.x; acc[1].y+=v.y; acc[1].z+=v.z; acc[1].w+=v.w; cnt[1]++; break;
                case 2: acc[2].x+=v.x; acc[2].y+=v.y; acc[2].z+=v.z; acc[2].w+=v.w; cnt[2]++; break;
                case 3: acc[3].x+=v.x; acc[3].y+=v.y; acc[3].z+=v.z; acc[3].w+=v.w; cnt[3]++; break;
                case 4: acc[4].x+=v.x; acc[4].y+=v.y; acc[4].z+=v.z; acc[4].w+=v.w; cnt[4]++; break;
                case 5: acc[5].x+=v.x; acc[5].y+=v.y; acc[5].z+=v.z; acc[5].w+=v.w; cnt[5]++; break;
                case 6: acc[6].x+=v.x; acc[6].y+=v.y; acc[6].z+=v.z; acc[6].w+=v.w; cnt[6]++; break;
                case 7: acc[7].x+=v.x; acc[7].y+=v.y; acc[7].z+=v.z; acc[7].w+=v.w; cnt[7]++; break;
            }
        }
    }

    #pragma unroll
    for (int c = 0; c < CODES; ++c) {
        *(float4*)&part[c][w][lane * 4] = acc[c];
        if (lane == 0) cnt_l[c][w] = (float)cnt[c];
    }
    __syncthreads();

    #pragma unroll
    for (int c = 0; c < CODES; ++c) {
        float sum = part[c][0][tid] + part[c][1][tid] + part[c][2][tid] + part[c][3][tid];
        if (USE_ATOMIC) {
            if (sum != 0.0f) atomicAdd(&dst[(long)(k0 + c) * Dd + tid], sum);
        } else {
            dst[((long)s * Kk + (k0 + c)) * Dd + tid] = sum;
        }
    }
    if (tid < CODES)
        atomicAdd(&counts[k0 + tid],
                  cnt_l[tid][0] + cnt_l[tid][1] + cnt_l[tid][2] + cnt_l[tid][3]);
}

// ============================================================
// Kernel G: new_cluster_size + total (single block)
// ============================================================
__global__ __launch_bounds__(256) void ema_cs_kernel(
    const float* __restrict__ cs, const float* __restrict__ counts,
    float* __restrict__ ncs, float* __restrict__ total_ws)
{
    __shared__ float red[256];
    int tid = threadIdx.x;
    float s = 0.0f;
    #pragma unroll
    for (int i = 0; i < 8; ++i) {
        int k = tid + i * 256;
        float v = cs[k] * DECAY + OMD * counts[k];
        ncs[k] = v;
        s += v;
    }
    red[tid] = s;
    __syncthreads();
    #pragma unroll
    for (int off = 128; off >= 1; off >>= 1) {
        if (tid < off) red[tid] += red[tid + off];
        __syncthreads();
    }
    if (tid == 0) total_ws[0] = red[0];
}

// ============================================================
// Kernel H: combine partials -> embed_sum; nea; ne.
// ============================================================
__global__ __launch_bounds__(256) void nea_ne_kernel(
    const float* __restrict__ ea, const float* __restrict__ partials,
    int nparts, const float* __restrict__ ncs, const float* __restrict__ total_ws,
    float* __restrict__ nea, float* __restrict__ ne)
{
    long g = ((long)blockIdx.x * 256 + threadIdx.x) * 4;
    int  k = (int)(g >> 8);
    int  d = (int)(g & 255);

    float4 sv = {0.f, 0.f, 0.f, 0.f};
    for (int p = 0; p < nparts; ++p) {
        float4 pv = *(const float4*)&partials[((long)p * Kk + k) * Dd + d];
        sv.x += pv.x; sv.y += pv.y; sv.z += pv.z; sv.w += pv.w;
    }

    float4 av = *(const float4*)&ea[g];
    float4 out_nea;
    out_nea.x = av.x * DECAY + OMD * sv.x;
    out_nea.y = av.y * DECAY + OMD * sv.y;
    out_nea.z = av.z * DECAY + OMD * sv.z;
    out_nea.w = av.w * DECAY + OMD * sv.w;
    *(float4*)&nea[g] = out_nea;

    float total = total_ws[0];
    float sm = (ncs[k] + EPSF) / (total + EPSF * (float)Kk) * total;
    float inv = 1.0f / sm;
    float4 out_ne;
    out_ne.x = out_nea.x * inv;
    out_ne.y = out_nea.y * inv;
    out_ne.z = out_nea.z * inv;
    out_ne.w = out_nea.w * inv;
    *(float4*)&ne[g] = out_ne;
}

// ============================================================
extern "C" void kernel_launch(void* const* d_in, const int* in_sizes, int n_in,
                              void* d_out, int out_size, void* d_ws, size_t ws_size,
                              hipStream_t stream)
{
    const float* x     = (const float*)d_in[0];
    const float* embed = (const float*)d_in[1];
    const float* cs    = (const float*)d_in[2];
    const float* ea    = (const float*)d_in[3];

    float* out   = (float*)d_out;
    float* quant = out + OUT_QUANT;
    float* ind_f = out + OUT_IND;
    float* ncs   = out + OUT_NCS;
    float* nea   = out + OUT_NEA;
    float* ne    = out + OUT_NE;

    float* ws     = (float*)d_ws;
    float* counts = ws + WS_COUNTS;
    float* total  = ws + WS_TOTAL;
    float* ee     = ws + WS_EE;
    float* big    = ws + WS_BIG;     // embed_sum (atomic) or partials (ws path)

    // scratch inside d_out
    ushort* e_h = (ushort*)(out + OUT_NEA);     // 1MB fp16, nea region
    int*    qb  = (int*)(out + OUT_NE);

    const size_t need_partials =
        (size_t)(WS_BIG + (long)PARTS * Kk * Dd) * sizeof(float) + 1024;
    const bool use_ws_partials = ws_size >= need_partials;

    hipMemsetAsync(counts, 0, Kk * sizeof(float), stream);
    if (!use_ws_partials)
        hipMemsetAsync(big, 0, (size_t)Kk * Dd * sizeof(float), stream);

    convert_e_kernel<<<Kk / 4, 256, 0, stream>>>(embed, e_h, ee, qb);
    pass1_kernel<<<Nn / 64, 256, 0, stream>>>(x, e_h, embed, ee, ind_f, quant, qb);
    pass2_kernel<<<512, 256, 0, stream>>>(x, embed, ee, qb, ind_f, quant);
    if (use_ws_partials)
        segsum_kernel<0><<<(Kk / CODES) * PARTS, 256, 0, stream>>>(x, ind_f, big, counts);
    else
        segsum_kernel<1><<<(Kk / CODES) * PARTS, 256, 0, stream>>>(x, ind_f, big, counts);
    ema_cs_kernel<<<1, 256, 0, stream>>>(cs, counts, ncs, total);
    nea_ne_kernel<<<(Kk * Dd / 4) / 256, 256, 0, stream>>>(
        ea, big, use_ws_partials ? PARTS : 1, ncs, total, nea, ne);
}

// Round 8
// 490.994 us; speedup vs baseline: 1.3393x; 1.3393x over previous
//
#include <hip/hip_runtime.h>
#include <hip/hip_fp16.h>
#include <float.h>

#define DECAY 0.99f
#define OMD   0.01f
#define EPSF  1e-6f

constexpr int Bb = 8, Ss = 8192, Dd = 256, Kk = 2048;
constexpr int Nn = Bb * Ss;                 // 65536 rows

// ---- output layout (floats) ----
constexpr long OUT_QUANT = 0;                         // 16777216 floats
constexpr long OUT_IND   = (long)Nn * Dd;             // 16777216
constexpr long OUT_NCS   = OUT_IND + Nn;              // 16842752
constexpr long OUT_NEA   = OUT_NCS + Kk;              // 16844800
constexpr long OUT_NE    = OUT_NEA + (long)Kk * Dd;   // 17369088

// ---- workspace layout (floats) ----
constexpr long WS_COUNTS = 0;                         // K
constexpr long WS_TOTAL  = 2048;                      // 1
constexpr long WS_EE     = 2112;                      // K
constexpr long WS_BIG    = 4160;                      // embed_sum (atomic path)
                                                      // or 8 partials (ws path)
constexpr int  PARTS     = 8;                         // strip split for segsum
constexpr int  CODES     = 8;                         // codes per segsum block

typedef __attribute__((ext_vector_type(8))) short short8;
typedef __attribute__((ext_vector_type(8))) _Float16 half8;
typedef __attribute__((ext_vector_type(4))) float floatx4;

// fp16 single-pass certainty window: per-dist error std ~0.018, realistic max
// over all rows ~0.13; rows whose approx top-2 gap <= WINDOW get an exact
// fp32 rescan in pass 2. 0.5 = ~20 sigma margin. Also makes partition-merge
// order tie-safe: any near-tie (<=WINDOW) is rescanned exactly.
#define WINDOW 0.5f

// async global->LDS, 16B per lane, LDS dest = wave-uniform base + lane*16
__device__ __forceinline__ void gl_lds(const ushort* g, ushort* l)
{
    __builtin_amdgcn_global_load_lds(
        (const __attribute__((address_space(1))) void*)g,
        (__attribute__((address_space(3))) void*)l,
        16, 0, 0);
}

__device__ __forceinline__ ushort f2h(float v)
{
    __half h = __float2half(v);
    return *(ushort*)&h;
}

// ============================================================
// Kernel B: embed -> e_h (fp16), ee[k] = sum_d embed[k][d]^2, and
// (block 0) reset the pass-2 ambiguity queue counter.
// ============================================================
__global__ __launch_bounds__(256) void convert_e_kernel(
    const float* __restrict__ embed, ushort* __restrict__ e_h,
    float* __restrict__ ee, int* __restrict__ qbase)
{
    if (blockIdx.x == 0 && threadIdx.x == 0) qbase[0] = 0;
    int row  = blockIdx.x * 4 + (threadIdx.x >> 6);
    int lane = threadIdx.x & 63;
    long base = (long)row * Dd + lane * 4;
    float4 v = *(const float4*)&embed[base];
    float s = v.x * v.x + v.y * v.y + v.z * v.z + v.w * v.w;
    ushort4 h;
    h.x = f2h(v.x); h.y = f2h(v.y); h.z = f2h(v.z); h.w = f2h(v.w);
    *(ushort4*)&e_h[base] = h;
    #pragma unroll
    for (int off = 32; off >= 1; off >>= 1)
        s += __shfl_xor(s, off, 64);
    if (lane == 0) ee[row] = s;
}

// ============================================================
// Kernel C (pass 1): fp16 MFMA distance + top-2 argmin + fused quant gather.
//
// v11 (round 8): round-3 verified geometry (128 rows x 256-code tiles,
// K=32 phases, XOR swizzle, 0 conflicts, 2 waves/EU) + fp16 single-pass
// + T3 minimum 2-phase pipeline + T14 async A-staging:
//   per phase p: issue x-loads(p+1) into regs + B gl_lds(p+1) into buf^1;
//   compute phase p from buf; cvt+ds_write A(p+1) into buf^1; ONE
//   __syncthreads (its vmcnt/lgkm drain now waits on loads that had a
//   full compute phase to land). NO sched_barrier, NO manual vmcnt
//   (round-2 lesson), NO occupancy pin beyond the verified (2,2).
//   convert_x deleted: fp32->fp16 conversion fused into A staging
//   (x is L3-resident; 8x fp32 re-read is L3-served).
// ============================================================
__global__ __attribute__((amdgpu_waves_per_eu(2, 2))) __launch_bounds__(256)
void pass1_kernel(
    const float* __restrict__ x, const ushort* __restrict__ e_h,
    const float* __restrict__ embed, const float* __restrict__ ee,
    float* __restrict__ ind_out, float* __restrict__ quant,
    int* __restrict__ qbase)
{
    __shared__ __attribute__((aligned(16))) ushort ah[2][128 * 32]; // 2x8KB
    __shared__ __attribute__((aligned(16))) ushort bh[2][256 * 32]; // 2x16KB
    __shared__ float redv[2][128];
    __shared__ float red2[2][128];
    __shared__ int   redi[2][128];
    __shared__ int   idxs[128];

    const int tid  = threadIdx.x;
    const int lane = tid & 63;
    const int quad = lane >> 4;
    const int l15  = lane & 15;
    const int w    = tid >> 6;
    const int wy   = w >> 1;
    const int wx   = w & 1;
    const long row0 = (long)blockIdx.x * 128;

    // B staging source pre-swizzle (gl_lds; verified round 3, 0 conflicts):
    // lane covers (rloc = lane>>2, slot = lane&3) of a 16-row segment;
    // slot s holds source chunk s ^ ((row>>1)&3) = s ^ ((lane>>3)&3).
    const int rloc   = lane >> 2;
    const int cchunk = (lane & 3) ^ ((rloc >> 1) & 3);
    const int gcoff  = rloc * 256 + cchunk * 8;   // ushorts from (seg row0, kcol)

    // A reg-staging: lane handles sub-row a_r, source chunk a_c; dest slot
    // swizzled the same way (write-side of the same involution).
    const int a_r    = lane >> 2;
    const int a_c    = lane & 3;
    const int a_slot = a_c ^ ((lane >> 3) & 3);

    // fragment read swizzle: row = 16k + l15 -> (row>>1)&3 = (l15>>1)&3
    const int sread = (l15 >> 1) & 3;
    const int aoff0 = ((wy * 64 + l15) << 5) + ((quad ^ sread) << 3);
    const int boff0 = ((wx * 128 + l15) << 5) + ((quad ^ sread) << 3);

#define STAGE_B(b, ctn, kcn) do {                                          \
    const long bb = (((long)(ctn) * 256) << 8) + (kcn) * 32 + gcoff;       \
    gl_lds(&e_h[bb + ((long)w << 12)],        &bh[b][w * 512]);            \
    gl_lds(&e_h[bb + ((long)(w + 4) << 12)],  &bh[b][(w + 4) * 512]);      \
    gl_lds(&e_h[bb + ((long)(w + 8) << 12)],  &bh[b][(w + 8) * 512]);      \
    gl_lds(&e_h[bb + ((long)(w + 12) << 12)], &bh[b][(w + 12) * 512]);     \
} while (0)

#define STAGE_A_LOAD(kcn) do {                                             \
    const long ar = ((row0 + w * 16 + a_r) << 8) + (kcn) * 32 + a_c * 8;   \
    const long br = ((row0 + (w + 4) * 16 + a_r) << 8) + (kcn) * 32 + a_c * 8; \
    pa0 = *(const float4*)&x[ar]; pa1 = *(const float4*)&x[ar + 4];        \
    pb0 = *(const float4*)&x[br]; pb1 = *(const float4*)&x[br + 4];        \
} while (0)

#define STAGE_A_WRITE(b) do {                                              \
    half8 h0, h1;                                                          \
    h0[0]=(_Float16)pa0.x; h0[1]=(_Float16)pa0.y;                          \
    h0[2]=(_Float16)pa0.z; h0[3]=(_Float16)pa0.w;                          \
    h0[4]=(_Float16)pa1.x; h0[5]=(_Float16)pa1.y;                          \
    h0[6]=(_Float16)pa1.z; h0[7]=(_Float16)pa1.w;                          \
    h1[0]=(_Float16)pb0.x; h1[1]=(_Float16)pb0.y;                          \
    h1[2]=(_Float16)pb0.z; h1[3]=(_Float16)pb0.w;                          \
    h1[4]=(_Float16)pb1.x; h1[5]=(_Float16)pb1.y;                          \
    h1[6]=(_Float16)pb1.z; h1[7]=(_Float16)pb1.w;                          \
    *(half8*)&ah[b][(w * 16 + a_r) * 32 + a_slot * 8] = h0;                \
    *(half8*)&ah[b][((w + 4) * 16 + a_r) * 32 + a_slot * 8] = h1;          \
} while (0)

    float4 pa0, pa1, pb0, pb1;

    float bestv[16], best2v[16];
    int   besti[16];
    #pragma unroll
    for (int i = 0; i < 16; ++i) { bestv[i] = FLT_MAX; best2v[i] = FLT_MAX; besti[i] = 0; }

    // prologue: phase 0 into buf 0
    STAGE_A_LOAD(0);
    STAGE_B(0, 0, 0);
    STAGE_A_WRITE(0);
    __syncthreads();

    int buf = 0;
    for (int ct = 0; ct < 8; ++ct) {
        floatx4 acc[4][8];
        #pragma unroll
        for (int rt = 0; rt < 4; ++rt)
            #pragma unroll
            for (int jt = 0; jt < 8; ++jt)
                acc[rt][jt] = (floatx4){0.f, 0.f, 0.f, 0.f};

        for (int kc = 0; kc < 8; ++kc) {
            const int p  = ct * 8 + kc;
            const int pn = p + 1;
            const bool more = (pn < 64);
            if (more) {
                STAGE_A_LOAD(pn & 7);
                STAGE_B(buf ^ 1, pn >> 3, pn & 7);
            }

            half8 af[4];
            #pragma unroll
            for (int rt = 0; rt < 4; ++rt)
                af[rt] = *(const half8*)&ah[buf][aoff0 + (rt << 9)];
            #pragma unroll
            for (int jt = 0; jt < 8; ++jt) {
                half8 bf = *(const half8*)&bh[buf][boff0 + (jt << 9)];
                #pragma unroll
                for (int rt = 0; rt < 4; ++rt)
                    acc[rt][jt] = __builtin_amdgcn_mfma_f32_16x16x32_f16(
                        af[rt], bf, acc[rt][jt], 0, 0, 0);
            }

            if (more) STAGE_A_WRITE(buf ^ 1);
            __syncthreads();
            buf ^= 1;
        }

        #pragma unroll
        for (int jt = 0; jt < 8; ++jt) {
            int c = ct * 256 + wx * 128 + jt * 16 + l15;
            float eec = ee[c];
            #pragma unroll
            for (int rt = 0; rt < 4; ++rt) {
                #pragma unroll
                for (int reg = 0; reg < 4; ++reg) {
                    float s = eec - 2.0f * acc[rt][jt][reg];
                    int slot = rt * 4 + reg;
                    if (s < bestv[slot]) {
                        best2v[slot] = bestv[slot];
                        bestv[slot] = s; besti[slot] = c;
                    } else {
                        best2v[slot] = fminf(best2v[slot], s);
                    }
                }
            }
        }
    }
#undef STAGE_B
#undef STAGE_A_LOAD
#undef STAGE_A_WRITE

    // 16-lane top-2 reduce (cols within wave partition)
    #pragma unroll
    for (int slot = 0; slot < 16; ++slot) {
        float bv = bestv[slot]; int bi = besti[slot]; float b2 = best2v[slot];
        #pragma unroll
        for (int off = 8; off >= 1; off >>= 1) {
            float ov  = __shfl_xor(bv, off, 16);
            int   oi  = __shfl_xor(bi, off, 16);
            float ov2 = __shfl_xor(b2, off, 16);
            float nm2 = fminf(fminf(b2, ov2), fmaxf(bv, ov));
            if (ov < bv) { bv = ov; bi = oi; }
            b2 = nm2;
        }
        bestv[slot] = bv; besti[slot] = bi; best2v[slot] = b2;
    }

    if (l15 == 0) {
        #pragma unroll
        for (int rt = 0; rt < 4; ++rt)
            #pragma unroll
            for (int reg = 0; reg < 4; ++reg) {
                int rl = wy * 64 + rt * 16 + quad * 4 + reg;
                int slot = rt * 4 + reg;
                redv[wx][rl] = bestv[slot];
                red2[wx][rl] = best2v[slot];
                redi[wx][rl] = besti[slot];
            }
    }
    __syncthreads();
    if (tid < 128) {
        float v0 = redv[0][tid], v1 = redv[1][tid];
        float s0 = red2[0][tid], s1 = red2[1][tid];
        float m1, m2; int mi;
        if (v0 <= v1) { m1 = v0; mi = redi[0][tid]; m2 = fminf(fminf(s0, s1), v1); }
        else          { m1 = v1; mi = redi[1][tid]; m2 = fminf(fminf(s0, s1), v0); }
        long rowAbs = row0 + tid;
        ind_out[rowAbs] = (float)mi;
        idxs[tid] = mi;
        if (m2 - m1 <= WINDOW) {
            int q = atomicAdd(qbase, 1);
            qbase[1 + q] = (int)rowAbs;
        }
    }
    __syncthreads();

    // ---- fused quant gather: quant[row] = embed[ind[row]] ----
    #pragma unroll
    for (int rr = 0; rr < 32; ++rr) {
        int r = w * 32 + rr;
        int idx = idxs[r];
        float4 ev = *(const float4*)&embed[(long)idx * Dd + lane * 4];
        *(float4*)&quant[(row0 + r) * Dd + lane * 4] = ev;
    }
}

// ============================================================
// Kernel D (pass 2): exact fp32 rescan of ambiguous rows (8-row batches),
// also rewriting quant for every queued row. (round-6 v2, spill-free)
// ============================================================
constexpr int RB = 8;
__global__ __launch_bounds__(256) void pass2_kernel(
    const float* __restrict__ x, const float* __restrict__ embed,
    const float* __restrict__ ee, const int* __restrict__ qbase,
    float* __restrict__ ind_out, float* __restrict__ quant)
{
    __shared__ float xs[RB][256];
    __shared__ float sv[RB][256];
    __shared__ int   si[RB][256];
    const int tid = threadIdx.x;
    const int count = qbase[0];

    for (int q0 = blockIdx.x * RB; q0 < count; q0 += gridDim.x * RB) {
        const int nr = (count - q0 < RB) ? (count - q0) : RB;
        __syncthreads();
        for (int r = 0; r < nr; ++r)
            xs[r][tid] = x[(long)qbase[1 + q0 + r] * Dd + tid];
        __syncthreads();

        float bv[RB]; int bi[RB];
        #pragma unroll
        for (int r = 0; r < RB; ++r) { bv[r] = FLT_MAX; bi[r] = 0; }

        for (int i = 0; i < Kk / 256; ++i) {
            const int c = i * 256 + tid;
            const float4* er = (const float4*)&embed[(long)c * Dd];
            float dot[RB];
            #pragma unroll
            for (int r = 0; r < RB; ++r) dot[r] = 0.0f;
            for (int d = 0; d < Dd / 4; ++d) {
                float4 e4 = er[d];
                #pragma unroll
                for (int r = 0; r < RB; ++r) {
                    float4 x4 = *(const float4*)&xs[r][d * 4];
                    dot[r] += e4.x * x4.x + e4.y * x4.y + e4.z * x4.z + e4.w * x4.w;
                }
            }
            float eec = ee[c];
            #pragma unroll
            for (int r = 0; r < RB; ++r) {
                float s = eec - 2.0f * dot[r];
                if (s < bv[r]) { bv[r] = s; bi[r] = c; }
            }
        }

        #pragma unroll
        for (int r = 0; r < RB; ++r) { sv[r][tid] = bv[r]; si[r][tid] = bi[r]; }
        __syncthreads();
        for (int off = 128; off >= 1; off >>= 1) {
            if (tid < off) {
                #pragma unroll
                for (int r = 0; r < RB; ++r) {
                    float v2 = sv[r][tid + off]; int i2 = si[r][tid + off];
                    if (v2 < sv[r][tid] || (v2 == sv[r][tid] && i2 < si[r][tid])) {
                        sv[r][tid] = v2; si[r][tid] = i2;
                    }
                }
            }
            __syncthreads();
        }
        if (tid < nr)
            ind_out[qbase[1 + q0 + tid]] = (float)si[tid][0];
        // rewrite quant for queued rows (exact final index)
        for (int r = 0; r < nr; ++r) {
            int code = si[r][0];
            long row = qbase[1 + q0 + r];
            quant[row * Dd + tid] = embed[(long)code * Dd + tid];
        }
        __syncthreads();
    }
}

// ============================================================
// Kernel F: pull-based segmented sum, CODES=8 codes per block.
// ============================================================
template <int USE_ATOMIC>
__global__ __launch_bounds__(256) void segsum_kernel(
    const float* __restrict__ x, const float* __restrict__ ind_f,
    float* __restrict__ dst, float* __restrict__ counts)
{
    __shared__ float part[CODES][4][256];   // 32KB
    __shared__ float cnt_l[CODES][4];
    const int tid  = threadIdx.x;
    const int w    = tid >> 6;
    const int lane = tid & 63;
    const int k0   = (blockIdx.x >> 3) * CODES;
    const int s    = blockIdx.x & 7;

    constexpr int STRIP = Nn / PARTS;          // 8192 rows
    constexpr int WAVE_ROWS = STRIP / 4;       // 2048 rows per wave
    const int base0 = s * STRIP + w * WAVE_ROWS;

    float4 acc[CODES];
    int    cnt[CODES];
    #pragma unroll
    for (int c = 0; c < CODES; ++c) { acc[c] = (float4){0.f,0.f,0.f,0.f}; cnt[c] = 0; }

    for (int win = 0; win < WAVE_ROWS; win += 64) {
        int idx = (int)ind_f[base0 + win + lane];
        unsigned rel = (unsigned)(idx - k0);
        unsigned long long m = __ballot(rel < (unsigned)CODES);
        while (m) {
            int l = __ffsll((unsigned long long)m) - 1;
            m &= m - 1;
            int code = __shfl((int)rel, l, 64);   // wave-uniform
            long row = base0 + win + l;
            float4 v = *(const float4*)&x[row * Dd + lane * 4];
            switch (code) {
                case 0: acc[0].x+=v.x; acc[0].y+=v.y; acc[0].z+=v.z; acc[0].w+=v.w; cnt[0]++; break;
                case 1: acc[1].x+=v.x; acc[1].y+=v.y; acc[1].z+=v.z; acc[1].w+=v.w; cnt[1]++; break;
                case 2: acc[2].x+=v.x; acc[2].y+=v.y; acc[2].z+=v.z; acc[2].w+=v.w; cnt[2]++; break;
                case 3: acc[3].x+=v.x; acc[3].y+=v.y; acc[3].z+=v.z; acc[3].w+=v.w; cnt[3]++; break;
                case 4: acc[4].x+=v.x; acc[4].y+=v.y; acc[4].z+=v.z; acc[4].w+=v.w; cnt[4]++; break;
                case 5: acc[5].x+=v.x; acc[5].y+=v.y; acc[5].z+=v.z; acc[5].w+=v.w; cnt[5]++; break;
                case 6: acc[6].x+=v.x; acc[6].y+=v.y; acc[6].z+=v.z; acc[6].w+=v.w; cnt[6]++; break;
                case 7: acc[7].x+=v.x; acc[7].y+=v.y; acc[7].z+=v.z; acc[7].w+=v.w; cnt[7]++; break;
            }
        }
    }

    #pragma unroll
    for (int c = 0; c < CODES; ++c) {
        *(float4*)&part[c][w][lane * 4] = acc[c];
        if (lane == 0) cnt_l[c][w] = (float)cnt[c];
    }
    __syncthreads();

    #pragma unroll
    for (int c = 0; c < CODES; ++c) {
        float sum = part[c][0][tid] + part[c][1][tid] + part[c][2][tid] + part[c][3][tid];
        if (USE_ATOMIC) {
            if (sum != 0.0f) atomicAdd(&dst[(long)(k0 + c) * Dd + tid], sum);
        } else {
            dst[((long)s * Kk + (k0 + c)) * Dd + tid] = sum;
        }
    }
    if (tid < CODES)
        atomicAdd(&counts[k0 + tid],
                  cnt_l[tid][0] + cnt_l[tid][1] + cnt_l[tid][2] + cnt_l[tid][3]);
}

// ============================================================
// Kernel G: new_cluster_size + total (single block)
// ============================================================
__global__ __launch_bounds__(256) void ema_cs_kernel(
    const float* __restrict__ cs, const float* __restrict__ counts,
    float* __restrict__ ncs, float* __restrict__ total_ws)
{
    __shared__ float red[256];
    int tid = threadIdx.x;
    float s = 0.0f;
    #pragma unroll
    for (int i = 0; i < 8; ++i) {
        int k = tid + i * 256;
        float v = cs[k] * DECAY + OMD * counts[k];
        ncs[k] = v;
        s += v;
    }
    red[tid] = s;
    __syncthreads();
    #pragma unroll
    for (int off = 128; off >= 1; off >>= 1) {
        if (tid < off) red[tid] += red[tid + off];
        __syncthreads();
    }
    if (tid == 0) total_ws[0] = red[0];
}

// ============================================================
// Kernel H: combine partials -> embed_sum; nea; ne.
// ============================================================
__global__ __launch_bounds__(256) void nea_ne_kernel(
    const float* __restrict__ ea, const float* __restrict__ partials,
    int nparts, const float* __restrict__ ncs, const float* __restrict__ total_ws,
    float* __restrict__ nea, float* __restrict__ ne)
{
    long g = ((long)blockIdx.x * 256 + threadIdx.x) * 4;
    int  k = (int)(g >> 8);
    int  d = (int)(g & 255);

    float4 sv = {0.f, 0.f, 0.f, 0.f};
    for (int p = 0; p < nparts; ++p) {
        float4 pv = *(const float4*)&partials[((long)p * Kk + k) * Dd + d];
        sv.x += pv.x; sv.y += pv.y; sv.z += pv.z; sv.w += pv.w;
    }

    float4 av = *(const float4*)&ea[g];
    float4 out_nea;
    out_nea.x = av.x * DECAY + OMD * sv.x;
    out_nea.y = av.y * DECAY + OMD * sv.y;
    out_nea.z = av.z * DECAY + OMD * sv.z;
    out_nea.w = av.w * DECAY + OMD * sv.w;
    *(float4*)&nea[g] = out_nea;

    float total = total_ws[0];
    float sm = (ncs[k] + EPSF) / (total + EPSF * (float)Kk) * total;
    float inv = 1.0f / sm;
    float4 out_ne;
    out_ne.x = out_nea.x * inv;
    out_ne.y = out_nea.y * inv;
    out_ne.z = out_nea.z * inv;
    out_ne.w = out_nea.w * inv;
    *(float4*)&ne[g] = out_ne;
}

// ============================================================
extern "C" void kernel_launch(void* const* d_in, const int* in_sizes, int n_in,
                              void* d_out, int out_size, void* d_ws, size_t ws_size,
                              hipStream_t stream)
{
    const float* x     = (const float*)d_in[0];
    const float* embed = (const float*)d_in[1];
    const float* cs    = (const float*)d_in[2];
    const float* ea    = (const float*)d_in[3];

    float* out   = (float*)d_out;
    float* quant = out + OUT_QUANT;
    float* ind_f = out + OUT_IND;
    float* ncs   = out + OUT_NCS;
    float* nea   = out + OUT_NEA;
    float* ne    = out + OUT_NE;

    float* ws     = (float*)d_ws;
    float* counts = ws + WS_COUNTS;
    float* total  = ws + WS_TOTAL;
    float* ee     = ws + WS_EE;
    float* big    = ws + WS_BIG;     // embed_sum (atomic) or partials (ws path)

    // scratch inside d_out
    ushort* e_h = (ushort*)(out + OUT_NEA);     // 1MB fp16, nea region
    int*    qb  = (int*)(out + OUT_NE);

    const size_t need_partials =
        (size_t)(WS_BIG + (long)PARTS * Kk * Dd) * sizeof(float) + 1024;
    const bool use_ws_partials = ws_size >= need_partials;

    hipMemsetAsync(counts, 0, Kk * sizeof(float), stream);
    if (!use_ws_partials)
        hipMemsetAsync(big, 0, (size_t)Kk * Dd * sizeof(float), stream);

    convert_e_kernel<<<Kk / 4, 256, 0, stream>>>(embed, e_h, ee, qb);
    pass1_kernel<<<Nn / 128, 256, 0, stream>>>(x, e_h, embed, ee, ind_f, quant, qb);
    pass2_kernel<<<512, 256, 0, stream>>>(x, embed, ee, qb, ind_f, quant);
    if (use_ws_partials)
        segsum_kernel<0><<<(Kk / CODES) * PARTS, 256, 0, stream>>>(x, ind_f, big, counts);
    else
        segsum_kernel<1><<<(Kk / CODES) * PARTS, 256, 0, stream>>>(x, ind_f, big, counts);
    ema_cs_kernel<<<1, 256, 0, stream>>>(cs, counts, ncs, total);
    nea_ne_kernel<<<(Kk * Dd / 4) / 256, 256, 0, stream>>>(
        ea, big, use_ws_partials ? PARTS : 1, ncs, total, nea, ne);
}